// Round 6
// baseline (162.473 us; speedup 1.0000x reference)
//
#include <hip/hip_runtime.h>
#include <hip/hip_bf16.h>

// MultiClassCostSensitiveLoss:
//   probs = softmax(y_pred, axis=1)           [N,3]
//   idx   = y_true + 1                        in {0,1,2}
//   se    = (probs[i, idx] - y_true)^2
//   out   = sum( wmap[idx] * se ),  wmap = {2.0, 0.5, 2.0}
//
// R5: single fused kernel.
//  - 2048 rows/block (24 KB pred LDS via global_load_lds w=16, labels direct
//    int4) -> 4096 blocks, per-block overhead halved, no tail at N=8.39M.
//  - last-block-done final reduce (threadfence + counter atomic) replaces the
//    second dispatch; 4-B counter zeroed by async memset each launch.

#define BLOCK 256
#define CHUNK_ROWS 2048
#define PRED_BYTES (CHUNK_ROWS * 12)   // 24576 B of preds per chunk
#define SEGS (PRED_BYTES / 1024)       // 24 x 1KB wave-level DMA transfers

typedef __attribute__((address_space(3))) void       lds_void;
typedef const __attribute__((address_space(1))) void gbl_void;

__device__ __forceinline__ void gload_lds16(const void* g, void* l) {
    // width must be a literal 16 -> global_load_lds_dwordx4
    __builtin_amdgcn_global_load_lds((gbl_void*)g, (lds_void*)l, 16, 0, 0);
}

__device__ __forceinline__ float row_loss(float a, float b, float c, int t) {
    const int idx = t + 1;                    // {0,1,2}
    const float m  = fmaxf(a, fmaxf(b, c));
    const float e0 = __expf(a - m);
    const float e1 = __expf(b - m);
    const float e2 = __expf(c - m);
    const float r  = __builtin_amdgcn_rcpf(e0 + e1 + e2);  // ~1e-5 rel err, fine
    const float en = (idx == 0) ? e0 : ((idx == 1) ? e1 : e2);
    const float p  = en * r;
    const float d  = p - (float)t;
    const float w  = (idx == 1) ? 0.5f : 2.0f;             // {2.0, 0.5, 2.0}
    return w * d * d;
}

__global__ __launch_bounds__(BLOCK) void mccs_fused(
    const float* __restrict__ y_pred,   // [N,3] row-major
    const int*   __restrict__ y_true,   // [N], values in {-1,0,1}
    float*       __restrict__ partials, // [gridDim.x]
    unsigned*    __restrict__ counter,  // [1], zeroed by memsetAsync
    float*       __restrict__ out,      // [1]
    int n)
{
    __shared__ __align__(16) char lds[PRED_BYTES];  // 24 KB
    const int t    = threadIdx.x;
    const int wave = t >> 6;
    const int lane = t & 63;

    const int nchunks = n / CHUNK_ROWS;
    float acc = 0.0f;

    // normally gridDim.x == nchunks -> exactly one iteration per block
    for (int c = blockIdx.x; c < nchunks; c += gridDim.x) {
        const long r0 = (long)c * CHUNK_ROWS;
        const char* gp = (const char*)y_pred + r0 * 12;  // 24576 B of preds

        // stage preds: 24 wave-level 1KB DMA transfers (6 per wave)
        #pragma unroll
        for (int j = 0; j < SEGS / 4; ++j) {
            const int seg = (wave * (SEGS / 4) + j) * 1024;
            gload_lds16(gp + seg + lane * 16, (char*)lds + seg);
        }

        // labels for rows 8t..8t+7: two lane-contiguous int4 loads
        const int4 ta = *(const int4*)(y_true + r0 + 8 * t);
        const int4 tb = *(const int4*)(y_true + r0 + 8 * t + 4);

        __syncthreads();   // drains vmcnt -> preds resident in LDS

        // thread t owns rows 8t..8t+7: floats [24t, 24t+24) = 12 x float2
        const float2* f2 = (const float2*)(lds + 96 * t);
        const float2 u0 = f2[0],  u1 = f2[1],  u2 = f2[2];
        const float2 u3 = f2[3],  u4 = f2[4],  u5 = f2[5];
        const float2 u6 = f2[6],  u7 = f2[7],  u8 = f2[8];
        const float2 u9 = f2[9],  uA = f2[10], uB = f2[11];

        acc += row_loss(u0.x, u0.y, u1.x, ta.x);
        acc += row_loss(u1.y, u2.x, u2.y, ta.y);
        acc += row_loss(u3.x, u3.y, u4.x, ta.z);
        acc += row_loss(u4.y, u5.x, u5.y, ta.w);
        acc += row_loss(u6.x, u6.y, u7.x, tb.x);
        acc += row_loss(u7.y, u8.x, u8.y, tb.y);
        acc += row_loss(u9.x, u9.y, uA.x, tb.z);
        acc += row_loss(uA.y, uB.x, uB.y, tb.w);

        __syncthreads();   // protect LDS if this block loops again
    }

    // tail rows (n % CHUNK_ROWS): direct global loads, grid-strided
    {
        const long tail = (long)nchunks * CHUNK_ROWS;
        for (long r = tail + (long)blockIdx.x * BLOCK + t; r < n;
             r += (long)gridDim.x * BLOCK) {
            acc += row_loss(y_pred[3 * r + 0], y_pred[3 * r + 1],
                            y_pred[3 * r + 2], y_true[r]);
        }
    }

    // wave-64 down-reduce, then LDS reduce of 4 wave partials
    #pragma unroll
    for (int off = 32; off > 0; off >>= 1)
        acc += __shfl_down(acc, off, 64);

    __shared__ float s_part[BLOCK / 64];
    if (lane == 0) s_part[wave] = acc;
    __syncthreads();

    __shared__ int s_last;
    if (t == 0) {
        float blk = 0.0f;
        #pragma unroll
        for (int w = 0; w < BLOCK / 64; ++w) blk += s_part[w];
        partials[blockIdx.x] = blk;        // plain store
        __threadfence();                    // device-scope: publish partial
        const unsigned old = atomicAdd(counter, 1u);
        s_last = (old == (unsigned)(gridDim.x - 1));
    }
    __syncthreads();

    if (s_last) {
        __threadfence();                    // see everyone's partials
        float s = 0.0f;
        for (int i = t; i < gridDim.x; i += BLOCK) s += partials[i];
        #pragma unroll
        for (int off = 32; off > 0; off >>= 1)
            s += __shfl_down(s, off, 64);
        if (lane == 0) s_part[wave] = s;
        __syncthreads();
        if (t == 0) {
            float tot = 0.0f;
            #pragma unroll
            for (int w = 0; w < BLOCK / 64; ++w) tot += s_part[w];
            *out = tot;
        }
    }
}

extern "C" void kernel_launch(void* const* d_in, const int* in_sizes, int n_in,
                              void* d_out, int out_size, void* d_ws, size_t ws_size,
                              hipStream_t stream)
{
    const float* y_pred = (const float*)d_in[0];
    const int*   y_true = (const int*)d_in[1];
    float*       out    = (float*)d_out;

    unsigned* counter = (unsigned*)d_ws;                 // 4 B at offset 0
    float*    parts   = (float*)((char*)d_ws + 16);      // aligned partials

    const int n = in_sizes[1];   // N samples (in_sizes[0] == 3*N)

    int nchunks = n / CHUNK_ROWS;               // 4096 at N=8.39M
    int blocks = nchunks < 1 ? 1 : nchunks;
    const int ws_cap = (int)((ws_size - 16) / sizeof(float));
    if (blocks > ws_cap) blocks = ws_cap;       // safety vs workspace size
    if (blocks > 8192) blocks = 8192;

    hipMemsetAsync(counter, 0, sizeof(unsigned), stream);
    mccs_fused<<<blocks, BLOCK, 0, stream>>>(y_pred, y_true, parts, counter,
                                             out, n);
}

// Round 7
// 118.436 us; speedup vs baseline: 1.3718x; 1.3718x over previous
//
#include <hip/hip_runtime.h>
#include <hip/hip_bf16.h>

// MultiClassCostSensitiveLoss:
//   probs = softmax(y_pred, axis=1)           [N,3]
//   idx   = y_true + 1                        in {0,1,2}
//   se    = (probs[i, idx] - y_true)^2
//   out   = sum( wmap[idx] * se ),  wmap = {2.0, 0.5, 2.0}
//
// R6: revert R5's fused last-block reduce (device-scope fence per block choked
// block-retirement pipelining -> 8x stall). Back to R4's streaming structure:
//  - 1024 rows/block, 8192 blocks, preds staged HBM->LDS via global_load_lds
//    w=16 (no data VGPRs, fully coalesced), one chunk per block.
//  - NEW: conflict-free LDS mapping — thread t owns rows {t+256k}: lane
//    dword-stride 3 mod 32 is bijective -> 2 lanes/bank = free (m136).
//  - NEW: no second kernel — each block atomicAdds its float partial to d_out
//    (zeroed by async memset). No fence: the atomic carries the value.

#define BLOCK 256
#define CHUNK_ROWS 1024
#define PRED_BYTES (CHUNK_ROWS * 12)   // 12288 B of preds per chunk

typedef __attribute__((address_space(3))) void       lds_void;
typedef const __attribute__((address_space(1))) void gbl_void;

__device__ __forceinline__ void gload_lds16(const void* g, void* l) {
    // width must be a literal 16 -> global_load_lds_dwordx4
    __builtin_amdgcn_global_load_lds((gbl_void*)g, (lds_void*)l, 16, 0, 0);
}

__device__ __forceinline__ float row_loss(float a, float b, float c, int t) {
    const int idx = t + 1;                    // {0,1,2}
    const float m  = fmaxf(a, fmaxf(b, c));
    const float e0 = __expf(a - m);
    const float e1 = __expf(b - m);
    const float e2 = __expf(c - m);
    const float r  = __builtin_amdgcn_rcpf(e0 + e1 + e2);  // ~1e-5 rel err, fine
    const float en = (idx == 0) ? e0 : ((idx == 1) ? e1 : e2);
    const float p  = en * r;
    const float d  = p - (float)t;
    const float w  = (idx == 1) ? 0.5f : 2.0f;             // {2.0, 0.5, 2.0}
    return w * d * d;
}

__global__ __launch_bounds__(BLOCK) void mccs_fused(
    const float* __restrict__ y_pred,   // [N,3] row-major
    const int*   __restrict__ y_true,   // [N], values in {-1,0,1}
    float*       __restrict__ out,      // [1], zeroed by memsetAsync
    int n)
{
    __shared__ __align__(16) char lds[PRED_BYTES];  // 12 KB
    const int t    = threadIdx.x;
    const int wave = t >> 6;
    const int lane = t & 63;

    const int nchunks = n / CHUNK_ROWS;
    float acc = 0.0f;

    // normally gridDim.x == nchunks -> exactly one iteration per block
    for (int c = blockIdx.x; c < nchunks; c += gridDim.x) {
        const long r0 = (long)c * CHUNK_ROWS;
        const char* gp = (const char*)y_pred + r0 * 12;  // 12288 B of preds

        // stage preds: 12 wave-level 1KB DMA transfers (3 per wave)
        #pragma unroll
        for (int j = 0; j < 3; ++j) {
            const int seg = (wave * 3 + j) * 1024;       // 1 KB per wave-instr
            gload_lds16(gp + seg + lane * 16, (char*)lds + seg);
        }

        // labels for rows t+256k: 4 lane-contiguous dword loads
        int tt[4];
        #pragma unroll
        for (int k = 0; k < 4; ++k)
            tt[k] = y_true[r0 + t + 256 * k];

        __syncthreads();   // drains vmcnt -> preds resident in LDS

        // thread t owns rows {t + 256k}: floats at dword 3*(t+256k)
        // lane dword-stride 3 (gcd(3,32)=1) -> 2 lanes/bank = conflict-free
        const float* lf = (const float*)lds;
        #pragma unroll
        for (int k = 0; k < 4; ++k) {
            const int r = t + 256 * k;
            acc += row_loss(lf[3 * r + 0], lf[3 * r + 1], lf[3 * r + 2], tt[k]);
        }

        __syncthreads();   // protect LDS if this block loops again
    }

    // tail rows (n % CHUNK_ROWS): direct global loads, grid-strided
    {
        const long tail = (long)nchunks * CHUNK_ROWS;
        for (long r = tail + (long)blockIdx.x * BLOCK + t; r < n;
             r += (long)gridDim.x * BLOCK) {
            acc += row_loss(y_pred[3 * r + 0], y_pred[3 * r + 1],
                            y_pred[3 * r + 2], y_true[r]);
        }
    }

    // wave-64 down-reduce, then LDS reduce of 4 wave partials
    #pragma unroll
    for (int off = 32; off > 0; off >>= 1)
        acc += __shfl_down(acc, off, 64);

    __shared__ float s_part[BLOCK / 64];
    if (lane == 0) s_part[wave] = acc;
    __syncthreads();

    if (t == 0) {
        float blk = 0.0f;
        #pragma unroll
        for (int w = 0; w < BLOCK / 64; ++w) blk += s_part[w];
        atomicAdd(out, blk);   // staggered arrivals; no fence needed
    }
}

extern "C" void kernel_launch(void* const* d_in, const int* in_sizes, int n_in,
                              void* d_out, int out_size, void* d_ws, size_t ws_size,
                              hipStream_t stream)
{
    const float* y_pred = (const float*)d_in[0];
    const int*   y_true = (const int*)d_in[1];
    float*       out    = (float*)d_out;

    const int n = in_sizes[1];   // N samples (in_sizes[0] == 3*N)

    int nchunks = n / CHUNK_ROWS;               // 8192 at N=8.39M
    int blocks = nchunks < 1 ? 1 : nchunks;
    if (blocks > 8192) blocks = 8192;

    // zero the single-float output each launch (graph-capture-safe)
    hipMemsetAsync(out, 0, sizeof(float), stream);
    mccs_fused<<<blocks, BLOCK, 0, stream>>>(y_pred, y_true, out, n);
}

// Round 8
// 29.249 us; speedup vs baseline: 5.5549x; 4.0493x over previous
//
#include <hip/hip_runtime.h>
#include <hip/hip_bf16.h>

// MultiClassCostSensitiveLoss:
//   probs = softmax(y_pred, axis=1)           [N,3]
//   idx   = y_true + 1                        in {0,1,2}
//   se    = (probs[i, idx] - y_true)^2
//   out   = sum( wmap[idx] * se ),  wmap = {2.0, 0.5, 2.0}
//
// R7: restore R4's proven two-kernel structure (28.6 us). R5/R6 post-mortem:
// per-block single-address atomics serialize at ~11 ns/RMW at the home L2 —
// 8192 blocks retiring in ~20 us queue into a ~90 us tail. Plain partial
// stores + a tiny reduce kernel avoid the serialization entirely.
//  - kernel1: 1024 rows/block, 8192 blocks, preds staged HBM->LDS via
//    global_load_lds w=16 (no data VGPRs, fully coalesced); labels direct
//    per-thread int4; conflict-free stride-3 LDS row mapping (rows t+256k).
//  - kernel2: 1024 threads reduce the 8192 partials, overwrite d_out.

#define BLOCK 256
#define CHUNK_ROWS 1024
#define PRED_BYTES (CHUNK_ROWS * 12)   // 12288 B of preds per chunk

typedef __attribute__((address_space(3))) void       lds_void;
typedef const __attribute__((address_space(1))) void gbl_void;

__device__ __forceinline__ void gload_lds16(const void* g, void* l) {
    // width must be a literal 16 -> global_load_lds_dwordx4
    __builtin_amdgcn_global_load_lds((gbl_void*)g, (lds_void*)l, 16, 0, 0);
}

__device__ __forceinline__ float row_loss(float a, float b, float c, int t) {
    const int idx = t + 1;                    // {0,1,2}
    const float m  = fmaxf(a, fmaxf(b, c));
    const float e0 = __expf(a - m);
    const float e1 = __expf(b - m);
    const float e2 = __expf(c - m);
    const float r  = __builtin_amdgcn_rcpf(e0 + e1 + e2);  // ~1e-5 rel err, fine
    const float en = (idx == 0) ? e0 : ((idx == 1) ? e1 : e2);
    const float p  = en * r;
    const float d  = p - (float)t;
    const float w  = (idx == 1) ? 0.5f : 2.0f;             // {2.0, 0.5, 2.0}
    return w * d * d;
}

__global__ __launch_bounds__(BLOCK) void mccs_partials(
    const float* __restrict__ y_pred,   // [N,3] row-major
    const int*   __restrict__ y_true,   // [N], values in {-1,0,1}
    float*       __restrict__ partials, // [gridDim.x]
    int n)
{
    __shared__ __align__(16) char lds[PRED_BYTES];  // 12 KB
    const int t    = threadIdx.x;
    const int wave = t >> 6;
    const int lane = t & 63;

    const int nchunks = n / CHUNK_ROWS;
    float acc = 0.0f;

    // normally gridDim.x == nchunks -> exactly one iteration per block
    for (int c = blockIdx.x; c < nchunks; c += gridDim.x) {
        const long r0 = (long)c * CHUNK_ROWS;
        const char* gp = (const char*)y_pred + r0 * 12;  // 12288 B of preds

        // stage preds: 12 wave-level 1KB DMA transfers (3 per wave)
        #pragma unroll
        for (int j = 0; j < 3; ++j) {
            const int seg = (wave * 3 + j) * 1024;       // 1 KB per wave-instr
            gload_lds16(gp + seg + lane * 16, (char*)lds + seg);
        }

        // labels for rows 4t..4t+3? No — rows {t+256k}; but int4 needs
        // contiguity, so load the 4 labels of rows t+256k as 4 coalesced
        // dword loads (each wave-instr covers 256 consecutive labels).
        int tt[4];
        #pragma unroll
        for (int k = 0; k < 4; ++k)
            tt[k] = y_true[r0 + t + 256 * k];

        __syncthreads();   // drains vmcnt -> preds resident in LDS

        // thread t owns rows {t + 256k}: floats at dword 3*(t+256k)
        // lane dword-stride 3 (gcd(3,32)=1) -> 2 lanes/bank = conflict-free
        const float* lf = (const float*)lds;
        #pragma unroll
        for (int k = 0; k < 4; ++k) {
            const int r = t + 256 * k;
            acc += row_loss(lf[3 * r + 0], lf[3 * r + 1], lf[3 * r + 2], tt[k]);
        }

        __syncthreads();   // protect LDS if this block loops again
    }

    // tail rows (n % CHUNK_ROWS): direct global loads, grid-strided
    {
        const long tail = (long)nchunks * CHUNK_ROWS;
        for (long r = tail + (long)blockIdx.x * BLOCK + t; r < n;
             r += (long)gridDim.x * BLOCK) {
            acc += row_loss(y_pred[3 * r + 0], y_pred[3 * r + 1],
                            y_pred[3 * r + 2], y_true[r]);
        }
    }

    // wave-64 down-reduce, then LDS reduce of 4 wave partials
    #pragma unroll
    for (int off = 32; off > 0; off >>= 1)
        acc += __shfl_down(acc, off, 64);

    __shared__ float s_part[BLOCK / 64];
    if (lane == 0) s_part[wave] = acc;
    __syncthreads();

    if (t == 0) {
        float blk = 0.0f;
        #pragma unroll
        for (int w = 0; w < BLOCK / 64; ++w) blk += s_part[w];
        partials[blockIdx.x] = blk;    // plain store — NO atomic (R6 lesson)
    }
}

#define FBLOCK 1024
__global__ __launch_bounds__(FBLOCK) void mccs_final(
    const float* __restrict__ partials, int nparts, float* __restrict__ out)
{
    float s = 0.0f;
    for (int i = threadIdx.x; i < nparts; i += FBLOCK) s += partials[i];
    #pragma unroll
    for (int off = 32; off > 0; off >>= 1)
        s += __shfl_down(s, off, 64);

    __shared__ float s_part[FBLOCK / 64];
    const int wave = threadIdx.x >> 6;
    if ((threadIdx.x & 63) == 0) s_part[wave] = s;
    __syncthreads();
    if (threadIdx.x == 0) {
        float tot = 0.0f;
        #pragma unroll
        for (int w = 0; w < FBLOCK / 64; ++w) tot += s_part[w];
        *out = tot;    // overwrite: no memset needed
    }
}

extern "C" void kernel_launch(void* const* d_in, const int* in_sizes, int n_in,
                              void* d_out, int out_size, void* d_ws, size_t ws_size,
                              hipStream_t stream)
{
    const float* y_pred = (const float*)d_in[0];
    const int*   y_true = (const int*)d_in[1];
    float*       out    = (float*)d_out;
    float*       parts  = (float*)d_ws;

    const int n = in_sizes[1];   // N samples (in_sizes[0] == 3*N)

    int nchunks = n / CHUNK_ROWS;               // 8192 at N=8.39M
    int blocks = nchunks < 1 ? 1 : nchunks;
    const int ws_cap = (int)(ws_size / sizeof(float));
    if (blocks > ws_cap) blocks = ws_cap;       // safety vs workspace size
    if (blocks > 8192) blocks = 8192;

    mccs_partials<<<blocks, BLOCK, 0, stream>>>(y_pred, y_true, parts, n);
    mccs_final<<<1, FBLOCK, 0, stream>>>(parts, blocks, out);
}

// Round 9
// 27.574 us; speedup vs baseline: 5.8923x; 1.0607x over previous
//
#include <hip/hip_runtime.h>
#include <hip/hip_bf16.h>

// MultiClassCostSensitiveLoss:
//   probs = softmax(y_pred, axis=1)           [N,3]
//   idx   = y_true + 1                        in {0,1,2}
//   se    = (probs[i, idx] - y_true)^2
//   out   = sum( wmap[idx] * se ),  wmap = {2.0, 0.5, 2.0}
//
// R8: R7 structure (two kernels, plain partial stores — NO per-block atomics,
// R6 lesson: single-line RMW serializes ~90/us) with halved block count:
//  - 2048 rows/block, 4096 blocks. Preds staged HBM->LDS via global_load_lds
//    w=16 (6 x 1KB DMA per wave, linear LDS dest), labels direct coalesced
//    dwords, conflict-free stride-3 LDS row mapping (rows t+256k, k=0..7).
//  - kernel2: 4096 partials = one float4 per thread, single load round.
// R5's 243us failure at this geometry is attributed to its fence+atomic
// epilogue (confirmed R6/R7), not the 2048-row structure.

#define BLOCK 256
#define CHUNK_ROWS 2048
#define PRED_BYTES (CHUNK_ROWS * 12)   // 24576 B of preds per chunk
#define SEGS_PER_WAVE 6                // 24 x 1KB segments / 4 waves

typedef __attribute__((address_space(3))) void       lds_void;
typedef const __attribute__((address_space(1))) void gbl_void;

__device__ __forceinline__ void gload_lds16(const void* g, void* l) {
    // width must be a literal 16 -> global_load_lds_dwordx4
    __builtin_amdgcn_global_load_lds((gbl_void*)g, (lds_void*)l, 16, 0, 0);
}

__device__ __forceinline__ float row_loss(float a, float b, float c, int t) {
    const int idx = t + 1;                    // {0,1,2}
    const float m  = fmaxf(a, fmaxf(b, c));
    const float e0 = __expf(a - m);
    const float e1 = __expf(b - m);
    const float e2 = __expf(c - m);
    const float r  = __builtin_amdgcn_rcpf(e0 + e1 + e2);  // ~1e-5 rel err, fine
    const float en = (idx == 0) ? e0 : ((idx == 1) ? e1 : e2);
    const float p  = en * r;
    const float d  = p - (float)t;
    const float w  = (idx == 1) ? 0.5f : 2.0f;             // {2.0, 0.5, 2.0}
    return w * d * d;
}

__global__ __launch_bounds__(BLOCK) void mccs_partials(
    const float* __restrict__ y_pred,   // [N,3] row-major
    const int*   __restrict__ y_true,   // [N], values in {-1,0,1}
    float*       __restrict__ partials, // [gridDim.x]
    int n)
{
    __shared__ __align__(16) char lds[PRED_BYTES];  // 24 KB
    const int t    = threadIdx.x;
    const int wave = t >> 6;
    const int lane = t & 63;

    const int nchunks = n / CHUNK_ROWS;
    float acc = 0.0f;

    // normally gridDim.x == nchunks -> exactly one iteration per block
    for (int c = blockIdx.x; c < nchunks; c += gridDim.x) {
        const long r0 = (long)c * CHUNK_ROWS;
        const char* gp = (const char*)y_pred + r0 * 12;  // 24576 B of preds

        // stage preds: 24 wave-level 1KB DMA transfers (6 per wave)
        #pragma unroll
        for (int j = 0; j < SEGS_PER_WAVE; ++j) {
            const int seg = (wave * SEGS_PER_WAVE + j) * 1024;
            gload_lds16(gp + seg + lane * 16, (char*)lds + seg);
        }

        // labels for rows {t+256k}: 8 coalesced dword loads (lane-contiguous)
        int tt[8];
        #pragma unroll
        for (int k = 0; k < 8; ++k)
            tt[k] = y_true[r0 + t + 256 * k];

        __syncthreads();   // drains vmcnt -> preds resident in LDS

        // thread t owns rows {t + 256k}: floats at dword 3*(t+256k)
        // lane dword-stride 3 (gcd(3,32)=1) -> 2 lanes/bank = conflict-free
        const float* lf = (const float*)lds;
        #pragma unroll
        for (int k = 0; k < 8; ++k) {
            const int r = t + 256 * k;
            acc += row_loss(lf[3 * r + 0], lf[3 * r + 1], lf[3 * r + 2], tt[k]);
        }

        __syncthreads();   // protect LDS if this block loops again
    }

    // tail rows (n % CHUNK_ROWS): direct global loads, grid-strided
    {
        const long tail = (long)nchunks * CHUNK_ROWS;
        for (long r = tail + (long)blockIdx.x * BLOCK + t; r < n;
             r += (long)gridDim.x * BLOCK) {
            acc += row_loss(y_pred[3 * r + 0], y_pred[3 * r + 1],
                            y_pred[3 * r + 2], y_true[r]);
        }
    }

    // wave-64 down-reduce, then LDS reduce of 4 wave partials
    #pragma unroll
    for (int off = 32; off > 0; off >>= 1)
        acc += __shfl_down(acc, off, 64);

    __shared__ float s_part[BLOCK / 64];
    if (lane == 0) s_part[wave] = acc;
    __syncthreads();

    if (t == 0) {
        float blk = 0.0f;
        #pragma unroll
        for (int w = 0; w < BLOCK / 64; ++w) blk += s_part[w];
        partials[blockIdx.x] = blk;    // plain store — NO atomic (R6 lesson)
    }
}

#define FBLOCK 1024
__global__ __launch_bounds__(FBLOCK) void mccs_final(
    const float* __restrict__ partials, int nparts, float* __restrict__ out)
{
    float s = 0.0f;
    // vectorized: one float4 per thread covers 4096 partials in one round
    const float4* p4 = (const float4*)partials;
    const int n4 = nparts >> 2;
    for (int i = threadIdx.x; i < n4; i += FBLOCK) {
        const float4 v = p4[i];
        s += (v.x + v.y) + (v.z + v.w);
    }
    // scalar tail (nparts % 4)
    for (int i = (n4 << 2) + threadIdx.x; i < nparts; i += FBLOCK)
        s += partials[i];

    #pragma unroll
    for (int off = 32; off > 0; off >>= 1)
        s += __shfl_down(s, off, 64);

    __shared__ float s_part[FBLOCK / 64];
    const int wave = threadIdx.x >> 6;
    if ((threadIdx.x & 63) == 0) s_part[wave] = s;
    __syncthreads();
    if (threadIdx.x == 0) {
        float tot = 0.0f;
        #pragma unroll
        for (int w = 0; w < FBLOCK / 64; ++w) tot += s_part[w];
        *out = tot;    // overwrite: no memset needed
    }
}

extern "C" void kernel_launch(void* const* d_in, const int* in_sizes, int n_in,
                              void* d_out, int out_size, void* d_ws, size_t ws_size,
                              hipStream_t stream)
{
    const float* y_pred = (const float*)d_in[0];
    const int*   y_true = (const int*)d_in[1];
    float*       out    = (float*)d_out;
    float*       parts  = (float*)d_ws;

    const int n = in_sizes[1];   // N samples (in_sizes[0] == 3*N)

    int nchunks = n / CHUNK_ROWS;               // 4096 at N=8.39M
    int blocks = nchunks < 1 ? 1 : nchunks;
    const int ws_cap = (int)(ws_size / sizeof(float));
    if (blocks > ws_cap) blocks = ws_cap;       // safety vs workspace size
    if (blocks > 8192) blocks = 8192;

    mccs_partials<<<blocks, BLOCK, 0, stream>>>(y_pred, y_true, parts, n);
    mccs_final<<<1, FBLOCK, 0, stream>>>(parts, blocks, out);
}

// Round 10
// 27.480 us; speedup vs baseline: 5.9124x; 1.0034x over previous
//
#include <hip/hip_runtime.h>
#include <hip/hip_bf16.h>

// MultiClassCostSensitiveLoss:
//   probs = softmax(y_pred, axis=1)           [N,3]
//   idx   = y_true + 1                        in {0,1,2}
//   se    = (probs[i, idx] - y_true)^2
//   out   = sum( wmap[idx] * se ),  wmap = {2.0, 0.5, 2.0}
//
// R9: final tail-halving of the proven R7/R8 structure (two kernels, plain
// partial stores — NO per-block atomics, R6 lesson: single-line RMW
// serializes ~90/us):
//  - 4096 rows/block, 512 threads, 48 KB LDS, 2048 blocks.
//    3 blocks/CU x 8 waves = 24 waves/CU (same TLP as R8's 6x4).
//  - Preds staged HBM->LDS via global_load_lds w=16 (6 x 1KB DMA per wave,
//    linear LDS dest); labels direct coalesced dwords; conflict-free
//    stride-3 LDS row mapping (rows t+512k, lane dword-stride 3, 2
//    lanes/bank = free per m136).
//  - kernel2: 2048 partials = one float4 per thread at 512 threads.

#define BLOCK 512
#define CHUNK_ROWS 4096
#define PRED_BYTES (CHUNK_ROWS * 12)   // 49152 B of preds per chunk
#define SEGS_PER_WAVE 6                // 48 x 1KB segments / 8 waves

typedef __attribute__((address_space(3))) void       lds_void;
typedef const __attribute__((address_space(1))) void gbl_void;

__device__ __forceinline__ void gload_lds16(const void* g, void* l) {
    // width must be a literal 16 -> global_load_lds_dwordx4
    __builtin_amdgcn_global_load_lds((gbl_void*)g, (lds_void*)l, 16, 0, 0);
}

__device__ __forceinline__ float row_loss(float a, float b, float c, int t) {
    const int idx = t + 1;                    // {0,1,2}
    const float m  = fmaxf(a, fmaxf(b, c));
    const float e0 = __expf(a - m);
    const float e1 = __expf(b - m);
    const float e2 = __expf(c - m);
    const float r  = __builtin_amdgcn_rcpf(e0 + e1 + e2);  // ~1e-5 rel err, fine
    const float en = (idx == 0) ? e0 : ((idx == 1) ? e1 : e2);
    const float p  = en * r;
    const float d  = p - (float)t;
    const float w  = (idx == 1) ? 0.5f : 2.0f;             // {2.0, 0.5, 2.0}
    return w * d * d;
}

__global__ __launch_bounds__(BLOCK) void mccs_partials(
    const float* __restrict__ y_pred,   // [N,3] row-major
    const int*   __restrict__ y_true,   // [N], values in {-1,0,1}
    float*       __restrict__ partials, // [gridDim.x]
    int n)
{
    __shared__ __align__(16) char lds[PRED_BYTES];  // 48 KB
    const int t    = threadIdx.x;
    const int wave = t >> 6;
    const int lane = t & 63;

    const int nchunks = n / CHUNK_ROWS;
    float acc = 0.0f;

    // normally gridDim.x == nchunks -> exactly one iteration per block
    for (int c = blockIdx.x; c < nchunks; c += gridDim.x) {
        const long r0 = (long)c * CHUNK_ROWS;
        const char* gp = (const char*)y_pred + r0 * 12;  // 49152 B of preds

        // stage preds: 48 wave-level 1KB DMA transfers (6 per wave)
        #pragma unroll
        for (int j = 0; j < SEGS_PER_WAVE; ++j) {
            const int seg = (wave * SEGS_PER_WAVE + j) * 1024;
            gload_lds16(gp + seg + lane * 16, (char*)lds + seg);
        }

        // labels for rows {t+512k}: 8 coalesced dword loads (lane-contiguous)
        int tt[8];
        #pragma unroll
        for (int k = 0; k < 8; ++k)
            tt[k] = y_true[r0 + t + 512 * k];

        __syncthreads();   // drains vmcnt -> preds resident in LDS

        // thread t owns rows {t + 512k}: floats at dword 3*(t+512k)
        // lane dword-stride 3 (gcd(3,32)=1) -> 2 lanes/bank = conflict-free
        const float* lf = (const float*)lds;
        #pragma unroll
        for (int k = 0; k < 8; ++k) {
            const int r = t + 512 * k;
            acc += row_loss(lf[3 * r + 0], lf[3 * r + 1], lf[3 * r + 2], tt[k]);
        }

        __syncthreads();   // protect LDS if this block loops again
    }

    // tail rows (n % CHUNK_ROWS): direct global loads, grid-strided
    {
        const long tail = (long)nchunks * CHUNK_ROWS;
        for (long r = tail + (long)blockIdx.x * BLOCK + t; r < n;
             r += (long)gridDim.x * BLOCK) {
            acc += row_loss(y_pred[3 * r + 0], y_pred[3 * r + 1],
                            y_pred[3 * r + 2], y_true[r]);
        }
    }

    // wave-64 down-reduce, then LDS reduce of 8 wave partials
    #pragma unroll
    for (int off = 32; off > 0; off >>= 1)
        acc += __shfl_down(acc, off, 64);

    __shared__ float s_part[BLOCK / 64];
    if (lane == 0) s_part[wave] = acc;
    __syncthreads();

    if (t == 0) {
        float blk = 0.0f;
        #pragma unroll
        for (int w = 0; w < BLOCK / 64; ++w) blk += s_part[w];
        partials[blockIdx.x] = blk;    // plain store — NO atomic (R6 lesson)
    }
}

#define FBLOCK 512
__global__ __launch_bounds__(FBLOCK) void mccs_final(
    const float* __restrict__ partials, int nparts, float* __restrict__ out)
{
    float s = 0.0f;
    // vectorized: one float4 per thread covers 2048 partials in one round
    const float4* p4 = (const float4*)partials;
    const int n4 = nparts >> 2;
    for (int i = threadIdx.x; i < n4; i += FBLOCK) {
        const float4 v = p4[i];
        s += (v.x + v.y) + (v.z + v.w);
    }
    // scalar tail (nparts % 4)
    for (int i = (n4 << 2) + threadIdx.x; i < nparts; i += FBLOCK)
        s += partials[i];

    #pragma unroll
    for (int off = 32; off > 0; off >>= 1)
        s += __shfl_down(s, off, 64);

    __shared__ float s_part[FBLOCK / 64];
    const int wave = threadIdx.x >> 6;
    if ((threadIdx.x & 63) == 0) s_part[wave] = s;
    __syncthreads();
    if (threadIdx.x == 0) {
        float tot = 0.0f;
        #pragma unroll
        for (int w = 0; w < FBLOCK / 64; ++w) tot += s_part[w];
        *out = tot;    // overwrite: no memset needed
    }
}

extern "C" void kernel_launch(void* const* d_in, const int* in_sizes, int n_in,
                              void* d_out, int out_size, void* d_ws, size_t ws_size,
                              hipStream_t stream)
{
    const float* y_pred = (const float*)d_in[0];
    const int*   y_true = (const int*)d_in[1];
    float*       out    = (float*)d_out;
    float*       parts  = (float*)d_ws;

    const int n = in_sizes[1];   // N samples (in_sizes[0] == 3*N)

    int nchunks = n / CHUNK_ROWS;               // 2048 at N=8.39M
    int blocks = nchunks < 1 ? 1 : nchunks;
    const int ws_cap = (int)(ws_size / sizeof(float));
    if (blocks > ws_cap) blocks = ws_cap;       // safety vs workspace size
    if (blocks > 8192) blocks = 8192;

    mccs_partials<<<blocks, BLOCK, 0, stream>>>(y_pred, y_true, parts, n);
    mccs_final<<<1, FBLOCK, 0, stream>>>(parts, blocks, out);
}